// Round 2
// baseline (88.044 us; speedup 1.0000x reference)
//
#include <hip/hip_runtime.h>
#include <hip/hip_bf16.h>
#include <cstddef>

#define BB 32
#define NN 2000
#define EE 128
#define HH 8
#define DD 16
#define NEGV (-1e9f)

// ws layout (floats):
// att/w   : [B][N][H]           off 0       512000
// qkh     : [B][H][E]           off 512000   32768
// qbk     : [B][H]              off 544768     256
// partial : [B][8chunk][H*E]    off 545024  262144
// logits  : [B][E]              off 807168    4096

__global__ __launch_bounds__(128) void k_qproj(
    const float* __restrict__ ds, const float* __restrict__ Wq, const float* __restrict__ bq,
    const float* __restrict__ Wk, const float* __restrict__ bk,
    float* __restrict__ qkh, float* __restrict__ qbk) {
  __shared__ float ds_s[EE];
  __shared__ float q_s[EE];
  const int b = blockIdx.x, t = threadIdx.x;
  ds_s[t] = ds[b * EE + t];
  __syncthreads();
  float acc = bq[t];
  for (int c = 0; c < EE; ++c) acc = fmaf(ds_s[c], Wq[c * EE + t], acc);
  q_s[t] = acc;
  __syncthreads();
  // qkh[b,h,e=t] = sum_d Wk[t][h*D+d] * q[h*D+d]   (row t of Wk, contiguous per thread)
  for (int h = 0; h < HH; ++h) {
    float s = 0.f;
#pragma unroll
    for (int d = 0; d < DD; ++d) s = fmaf(Wk[t * EE + h * DD + d], q_s[h * DD + d], s);
    qkh[(b * HH + h) * EE + t] = s;
  }
  if (t < HH) {
    float s = 0.f;
#pragma unroll
    for (int d = 0; d < DD; ++d) s += q_s[t * DD + d] * bk[t * DD + d];
    qbk[b * HH + t] = s;
  }
}

// att[b][n][h] = ne[b,n,:]. qkh[b,h,:] + qbk, masked, scaled
__global__ __launch_bounds__(256) void k_att(
    const float* __restrict__ ne, const int* __restrict__ mask,
    const float* __restrict__ qkh, const float* __restrict__ qbk,
    float* __restrict__ att) {
  const int b = blockIdx.y;
  const int n0 = blockIdx.x * 32;
  __shared__ float ne_s[32][129];
  __shared__ float qkh_s[HH][129];
  __shared__ float qbk_s[HH];
  const int t = threadIdx.x;
  for (int f = t; f < 32 * EE; f += 256) {
    int n = f >> 7, e = f & 127;
    int gn = n0 + n;
    ne_s[n][e] = (gn < NN) ? ne[((size_t)b * NN + gn) * EE + e] : 0.f;
  }
  for (int f = t; f < HH * EE; f += 256) {
    int h = f >> 7, e = f & 127;
    qkh_s[h][e] = qkh[(b * HH + h) * EE + e];
  }
  if (t < HH) qbk_s[t] = qbk[b * HH + t];
  __syncthreads();
  const int nl = t >> 3, h = t & 7;
  const int gn = n0 + nl;
  if (gn < NN) {
    float acc = qbk_s[h];
    for (int e = 0; e < EE; ++e) acc = fmaf(ne_s[nl][e], qkh_s[h][e], acc);
    const int m = mask[b * NN + gn];
    att[((size_t)b * NN + gn) * HH + h] = (m == 0) ? NEGV : acc * 0.25f;
  }
}

// softmax over n for each (b,h); in-place on att
__global__ __launch_bounds__(256) void k_softmax(float* __restrict__ att) {
  const int bh = blockIdx.x;
  const int b = bh >> 3, h = bh & 7;
  const int t = threadIdx.x;
  __shared__ float red[256];
  float mx = -INFINITY;
  for (int n = t; n < NN; n += 256) mx = fmaxf(mx, att[((size_t)b * NN + n) * HH + h]);
  red[t] = mx;
  __syncthreads();
  for (int s = 128; s > 0; s >>= 1) { if (t < s) red[t] = fmaxf(red[t], red[t + s]); __syncthreads(); }
  mx = red[0];
  __syncthreads();
  float sm = 0.f;
  for (int n = t; n < NN; n += 256) sm += expf(att[((size_t)b * NN + n) * HH + h] - mx);
  red[t] = sm;
  __syncthreads();
  for (int s = 128; s > 0; s >>= 1) { if (t < s) red[t] += red[t + s]; __syncthreads(); }
  const float inv = 1.f / red[0];
  for (int n = t; n < NN; n += 256) {
    size_t idx = ((size_t)b * NN + n) * HH + h;
    att[idx] = expf(att[idx] - mx) * inv;
  }
}

// partial[b][chunk][h*E+e] = sum over 250 nodes of w*ne
__global__ __launch_bounds__(128) void k_ctxe(
    const float* __restrict__ ne, const float* __restrict__ w,
    float* __restrict__ partial) {
  const int b = blockIdx.y;
  const int chunk = blockIdx.x;
  const int c0 = chunk * 250;
  __shared__ float w_s[250 * HH];
  const int t = threadIdx.x;
  for (int f = t; f < 250 * HH; f += 128) w_s[f] = w[((size_t)b * NN + c0) * HH + f];
  __syncthreads();
  float acc[HH] = {0.f, 0.f, 0.f, 0.f, 0.f, 0.f, 0.f, 0.f};
  for (int n = 0; n < 250; ++n) {
    const float nev = ne[((size_t)b * NN + c0 + n) * EE + t];
    const float* wp = &w_s[n * HH];
#pragma unroll
    for (int h = 0; h < HH; ++h) acc[h] = fmaf(wp[h], nev, acc[h]);
  }
#pragma unroll
  for (int h = 0; h < HH; ++h)
    partial[((size_t)b * 8 + chunk) * (HH * EE) + h * EE + t] = acc[h];
}

// per b: ctxE -> @Wv+bv -> @Wo+bo -> LN -> @Wp+bp -> logits[b][E]
__global__ __launch_bounds__(128) void k_head(
    const float* __restrict__ partial,
    const float* __restrict__ Wv, const float* __restrict__ bv,
    const float* __restrict__ Wo, const float* __restrict__ bo,
    const float* __restrict__ Wp, const float* __restrict__ bp,
    const float* __restrict__ ln_g, const float* __restrict__ ln_b,
    float* __restrict__ logits) {
  const int b = blockIdx.x, t = threadIdx.x;
  __shared__ float cE[HH * EE];
  __shared__ float buf[EE];
  __shared__ float red[128];
  for (int f = t; f < HH * EE; f += 128) {
    float s = 0.f;
    for (int c = 0; c < 8; ++c) s += partial[((size_t)b * 8 + c) * (HH * EE) + f];
    cE[f] = s;
  }
  __syncthreads();
  const int h = t >> 4;
  float acc = bv[t];
  for (int e = 0; e < EE; ++e) acc = fmaf(cE[h * EE + e], Wv[e * EE + t], acc);
  buf[t] = acc;
  __syncthreads();
  float acc2 = bo[t];
  for (int e = 0; e < EE; ++e) acc2 = fmaf(buf[e], Wo[e * EE + t], acc2);
  red[t] = acc2;
  __syncthreads();
  for (int s = 64; s > 0; s >>= 1) { if (t < s) red[t] += red[t + s]; __syncthreads(); }
  const float mu = red[0] / EE;
  __syncthreads();
  const float dv = acc2 - mu;
  red[t] = dv * dv;
  __syncthreads();
  for (int s = 64; s > 0; s >>= 1) { if (t < s) red[t] += red[t + s]; __syncthreads(); }
  const float rstd = rsqrtf(red[0] / EE + 1e-5f);
  __syncthreads();
  buf[t] = (acc2 - mu) * rstd * ln_g[t] + ln_b[t];
  __syncthreads();
  float acc3 = bp[t];
  for (int e = 0; e < EE; ++e) acc3 = fmaf(buf[e], Wp[e * EE + t], acc3);
  logits[b * EE + t] = acc3;
}

// scores[b][n] = logits . ne + penalty/bonus
__global__ __launch_bounds__(256) void k_scores(
    const float* __restrict__ ne, const float* __restrict__ logits,
    const int* __restrict__ visited, const int* __restrict__ prev_node,
    const int* __restrict__ all_visited, const float* __restrict__ ew,
    const float* __restrict__ sb_p, const float* __restrict__ rp_p,
    float* __restrict__ out) {
  const int b = blockIdx.y;
  const int n0 = blockIdx.x * 32;
  __shared__ __align__(16) float ne_s[32 * 132];
  __shared__ __align__(16) float lg_s[EE];
  const int t = threadIdx.x;
  for (int f = t; f < 32 * EE; f += 256) {
    int n = f >> 7, e = f & 127;
    int gn = n0 + n;
    ne_s[n * 132 + e] = (gn < NN) ? ne[((size_t)b * NN + gn) * EE + e] : 0.f;
  }
  if (t < EE) lg_s[t] = logits[b * EE + t];
  __syncthreads();
  const int nl = t >> 3, p = t & 7;
  float acc = 0.f;
#pragma unroll
  for (int i = 0; i < 4; ++i) {
    const float4 a = *reinterpret_cast<const float4*>(&ne_s[nl * 132 + p * 16 + i * 4]);
    const float4 l = *reinterpret_cast<const float4*>(&lg_s[p * 16 + i * 4]);
    acc += a.x * l.x + a.y * l.y + a.z * l.z + a.w * l.w;
  }
  acc += __shfl_down(acc, 4, 8);
  acc += __shfl_down(acc, 2, 8);
  acc += __shfl_down(acc, 1, 8);
  const int gn = n0 + nl;
  if (p == 0 && gn < NN) {
    float sc = acc;
    const bool av = all_visited[b] != 0;
    if (!av) {
      if (visited[b * NN + gn] != 0) sc = rp_p[0];
    } else {
      const int pv = prev_node[b];
      const float direct = ew[((size_t)b * NN + pv) * NN];
      const float via = ew[((size_t)b * NN + pv) * NN + gn] + ew[((size_t)b * NN + gn) * NN];
      if (via < direct) sc += sb_p[0] * (direct - via) / direct;
    }
    out[b * NN + gn] = sc;
  }
}

extern "C" void kernel_launch(void* const* d_in, const int* in_sizes, int n_in,
                              void* d_out, int out_size, void* d_ws, size_t ws_size,
                              hipStream_t stream) {
  const float* ds   = (const float*)d_in[0];
  const float* ne   = (const float*)d_in[1];
  const int*   mask = (const int*)d_in[2];
  const float* ew   = (const float*)d_in[3];
  const int*   visited = (const int*)d_in[4];
  const int*   prev = (const int*)d_in[5];
  const int*   allv = (const int*)d_in[6];
  const float* Wq = (const float*)d_in[7];
  const float* bq = (const float*)d_in[8];
  const float* Wk = (const float*)d_in[9];
  const float* bk = (const float*)d_in[10];
  const float* Wv = (const float*)d_in[11];
  const float* bv = (const float*)d_in[12];
  const float* Wo = (const float*)d_in[13];
  const float* bo = (const float*)d_in[14];
  const float* Wp = (const float*)d_in[15];
  const float* bp = (const float*)d_in[16];
  const float* ln_g = (const float*)d_in[17];
  const float* ln_b = (const float*)d_in[18];
  const float* sb = (const float*)d_in[19];
  const float* rp = (const float*)d_in[20];
  float* out = (float*)d_out;
  float* ws = (float*)d_ws;

  float* att     = ws;
  float* qkh     = ws + 512000;
  float* qbk     = ws + 544768;
  float* partial = ws + 545024;
  float* logits  = ws + 807168;

  k_qproj<<<BB, 128, 0, stream>>>(ds, Wq, bq, Wk, bk, qkh, qbk);
  k_att<<<dim3(63, BB), 256, 0, stream>>>(ne, mask, qkh, qbk, att);
  k_softmax<<<BB * HH, 256, 0, stream>>>(att);
  k_ctxe<<<dim3(8, BB), 128, 0, stream>>>(ne, att, partial);
  k_head<<<BB, 128, 0, stream>>>(partial, Wv, bv, Wo, bo, Wp, bp, ln_g, ln_b, logits);
  k_scores<<<dim3(63, BB), 256, 0, stream>>>(ne, logits, visited, prev, allv, ew, sb, rp, out);
}

// Round 3
// 63.947 us; speedup vs baseline: 1.3768x; 1.3768x over previous
//
#include <hip/hip_runtime.h>
#include <cstddef>

#define BB 32
#define NN 2000
#define EE 128
#define HH 8
#define DD 16
#define NCH 16
#define CHN 125
#define STN 64
#define NEGV (-1e9f)

// ws layout (floats):
// pctx  [B][NCH][H][E]  @ 0       524288
// pm    [B][NCH][H]     @ 524288    4096
// ps    [B][NCH][H]     @ 528384    4096
// logits[B][E]          @ 532480    4096

// K1: fused qproj + att + online softmax + ctxE partials. grid (NCH, B), 256 thr.
__global__ __launch_bounds__(256) void k_fused_att(
    const float* __restrict__ ds, const float* __restrict__ ne, const int* __restrict__ mask,
    const float* __restrict__ Wq, const float* __restrict__ bq,
    const float* __restrict__ Wk, const float* __restrict__ bk,
    float* __restrict__ pctx, float* __restrict__ pm, float* __restrict__ ps) {
  const int ch = blockIdx.x, b = blockIdx.y, t = threadIdx.x;
  __shared__ float ds_s[EE], q_s[EE];
  __shared__ float qkh_s[HH * 132];   // padded: bank-spread for b128 reads
  __shared__ float qbk_s[HH];
  __shared__ float ne_s[STN * 132];
  __shared__ float aw_s[STN * 9];     // att, then w, per subtile
  __shared__ float m_s[HH], s_s[HH];
  __shared__ int   mask_s[STN];

  if (t < EE) ds_s[t] = ds[b * EE + t];
  __syncthreads();
  if (t < EE) {
    float a0 = 0.f, a1 = 0.f, a2 = 0.f, a3 = 0.f;
    for (int c = 0; c < EE; c += 4) {
      a0 = fmaf(ds_s[c],     Wq[(c)     * EE + t], a0);
      a1 = fmaf(ds_s[c + 1], Wq[(c + 1) * EE + t], a1);
      a2 = fmaf(ds_s[c + 2], Wq[(c + 2) * EE + t], a2);
      a3 = fmaf(ds_s[c + 3], Wq[(c + 3) * EE + t], a3);
    }
    q_s[t] = bq[t] + ((a0 + a1) + (a2 + a3));
  }
  __syncthreads();
  for (int f = t; f < HH * EE; f += 256) {
    const int hh = f >> 7, e = f & 127;
    const float4* wk4 = (const float4*)(Wk + e * EE + hh * DD);
    const float4* qh4 = (const float4*)(q_s + hh * DD);
    float s = 0.f;
#pragma unroll
    for (int i = 0; i < 4; ++i) {
      const float4 w = wk4[i], q4 = qh4[i];
      s += w.x * q4.x + w.y * q4.y + w.z * q4.z + w.w * q4.w;
    }
    qkh_s[hh * 132 + e] = s;
  }
  if (t < HH) {
    float s = 0.f;
#pragma unroll
    for (int d = 0; d < DD; ++d) s += q_s[t * DD + d] * bk[t * DD + d];
    qbk_s[t] = s;
    m_s[t] = -INFINITY;
    s_s[t] = 0.f;
  }

  const int h = t >> 5, l = t & 31;   // softmax group h, lane + ctxE owner (h, e-quad l)
  float4 acc = make_float4(0.f, 0.f, 0.f, 0.f);
  const float4* ne4g = (const float4*)(ne + ((size_t)b * NN + ch * CHN) * EE);
  const int nbase = ch * CHN;

  for (int st = 0; st < 2; ++st) {
    const int s0 = st * STN;
    const int cnt = (CHN - s0 < STN) ? (CHN - s0) : STN;  // 64, 61
    __syncthreads();
    for (int f = t; f < cnt * 32; f += 256) {
      const int row = f >> 5, cq = f & 31;
      ((float4*)ne_s)[row * 33 + cq] = ne4g[(size_t)(s0 + row) * 32 + cq];
    }
    if (t < cnt) mask_s[t] = mask[b * NN + nbase + s0 + t];
    __syncthreads();
    // att for this subtile -> aw_s
#pragma unroll
    for (int pp = 0; pp < 2; ++pp) {
      const int p = t + pp * 256;
      if (p < cnt * 8) {
        const int n = p >> 3, hh = p & 7;
        const float4* nr = (const float4*)ne_s + n * 33;
        const float4* kr = (const float4*)qkh_s + hh * 33;
        float4 a4 = make_float4(0.f, 0.f, 0.f, 0.f);
#pragma unroll 8
        for (int i = 0; i < 32; ++i) {
          const float4 av = nr[i], kv = kr[i];
          a4.x = fmaf(av.x, kv.x, a4.x);
          a4.y = fmaf(av.y, kv.y, a4.y);
          a4.z = fmaf(av.z, kv.z, a4.z);
          a4.w = fmaf(av.w, kv.w, a4.w);
        }
        const float dot = (a4.x + a4.y) + (a4.z + a4.w);
        aw_s[n * 9 + hh] = mask_s[n] ? (dot + qbk_s[hh]) * 0.25f : NEGV;
      }
    }
    __syncthreads();
    // online softmax update for own h (32-lane group)
    float mx = -INFINITY;
    if (l < cnt) mx = aw_s[l * 9 + h];
    if (l + 32 < cnt) mx = fmaxf(mx, aw_s[(l + 32) * 9 + h]);
#pragma unroll
    for (int k = 16; k >= 1; k >>= 1) mx = fmaxf(mx, __shfl_xor(mx, k, 32));
    const float m_old = m_s[h];
    const float m_new = fmaxf(m_old, mx);
    const float r = expf(m_old - m_new);   // m_old=-inf -> 0 (m_new finite: NEGV floor)
    acc.x *= r; acc.y *= r; acc.z *= r; acc.w *= r;
    float sm = 0.f;
    if (l < cnt) { const float w = expf(aw_s[l * 9 + h] - m_new); aw_s[l * 9 + h] = w; sm += w; }
    if (l + 32 < cnt) { const float w = expf(aw_s[(l + 32) * 9 + h] - m_new); aw_s[(l + 32) * 9 + h] = w; sm += w; }
#pragma unroll
    for (int k = 16; k >= 1; k >>= 1) sm += __shfl_xor(sm, k, 32);
    if (l == 0) { s_s[h] = s_s[h] * r + sm; m_s[h] = m_new; }
    __syncthreads();
    // ctxE accumulate: acc[h][4l..4l+3] += sum_n w[n][h]*ne[n][...]
    const float4* nsr = (const float4*)ne_s;
    float4 accB = make_float4(0.f, 0.f, 0.f, 0.f);
    int n = 0;
    for (; n + 1 < cnt; n += 2) {
      const float w0 = aw_s[n * 9 + h], w1 = aw_s[(n + 1) * 9 + h];
      const float4 a0v = nsr[n * 33 + l], a1v = nsr[(n + 1) * 33 + l];
      acc.x = fmaf(w0, a0v.x, acc.x);  acc.y = fmaf(w0, a0v.y, acc.y);
      acc.z = fmaf(w0, a0v.z, acc.z);  acc.w = fmaf(w0, a0v.w, acc.w);
      accB.x = fmaf(w1, a1v.x, accB.x); accB.y = fmaf(w1, a1v.y, accB.y);
      accB.z = fmaf(w1, a1v.z, accB.z); accB.w = fmaf(w1, a1v.w, accB.w);
    }
    if (n < cnt) {
      const float w0 = aw_s[n * 9 + h];
      const float4 a0v = nsr[n * 33 + l];
      acc.x = fmaf(w0, a0v.x, acc.x);  acc.y = fmaf(w0, a0v.y, acc.y);
      acc.z = fmaf(w0, a0v.z, acc.z);  acc.w = fmaf(w0, a0v.w, acc.w);
    }
    acc.x += accB.x; acc.y += accB.y; acc.z += accB.z; acc.w += accB.w;
  }
  // write partials
  float4* po = (float4*)(pctx + (((size_t)b * NCH + ch) * HH + h) * EE) + l;
  *po = acc;
  if (t < HH) {
    pm[(b * NCH + ch) * HH + t] = m_s[t];
    ps[(b * NCH + ch) * HH + t] = s_s[t];
  }
}

// K2: merge chunk partials -> ctx -> Wv -> Wo -> LN -> Wp -> logits. grid B, 128 thr.
__global__ __launch_bounds__(128) void k_head(
    const float* __restrict__ pctx, const float* __restrict__ pm, const float* __restrict__ ps,
    const float* __restrict__ Wv, const float* __restrict__ bv,
    const float* __restrict__ Wo, const float* __restrict__ bo,
    const float* __restrict__ Wp, const float* __restrict__ bp,
    const float* __restrict__ ln_g, const float* __restrict__ ln_b,
    float* __restrict__ logits) {
  const int b = blockIdx.x, t = threadIdx.x;
  __shared__ float mg_s[HH], dn_s[HH];
  __shared__ float sc_s[NCH * HH];
  __shared__ float cE[HH * EE];
  __shared__ float buf[EE];
  __shared__ float red[128];
  if (t < HH) {
    float m = -INFINITY;
    for (int c = 0; c < NCH; ++c) m = fmaxf(m, pm[(b * NCH + c) * HH + t]);
    float dn = 0.f;
    for (int c = 0; c < NCH; ++c) dn += expf(pm[(b * NCH + c) * HH + t] - m) * ps[(b * NCH + c) * HH + t];
    mg_s[t] = m; dn_s[t] = dn;
  }
  __syncthreads();
  { const int c = t >> 3, hh = t & 7;
    sc_s[t] = expf(pm[(b * NCH + c) * HH + hh] - mg_s[hh]) / dn_s[hh]; }
  __syncthreads();
  for (int f = t; f < HH * EE; f += 128) {
    const int hh = f >> 7, e = f & 127;
    float s = 0.f;
#pragma unroll 4
    for (int c = 0; c < NCH; ++c)
      s += sc_s[c * HH + hh] * pctx[(((size_t)b * NCH + c) * HH + hh) * EE + e];
    cE[f] = s;
  }
  __syncthreads();
  const int hh2 = t >> 4;
  float acc = bv[t];
  for (int e = 0; e < EE; ++e) acc = fmaf(cE[hh2 * EE + e], Wv[e * EE + t], acc);
  buf[t] = acc;
  __syncthreads();
  float acc2 = bo[t];
  for (int e = 0; e < EE; ++e) acc2 = fmaf(buf[e], Wo[e * EE + t], acc2);
  red[t] = acc2;
  __syncthreads();
  for (int s = 64; s > 0; s >>= 1) { if (t < s) red[t] += red[t + s]; __syncthreads(); }
  const float mu = red[0] / EE;
  __syncthreads();
  red[t] = (acc2 - mu) * (acc2 - mu);
  __syncthreads();
  for (int s = 64; s > 0; s >>= 1) { if (t < s) red[t] += red[t + s]; __syncthreads(); }
  const float rstd = rsqrtf(red[0] / EE + 1e-5f);
  __syncthreads();
  buf[t] = (acc2 - mu) * rstd * ln_g[t] + ln_b[t];
  __syncthreads();
  float acc3 = bp[t];
  for (int e = 0; e < EE; ++e) acc3 = fmaf(buf[e], Wp[e * EE + t], acc3);
  logits[b * EE + t] = acc3;
}

// K3: scores. grid (16, B), 256 thr; each 32-lane group owns a node per iter.
__global__ __launch_bounds__(256) void k_scores(
    const float* __restrict__ ne, const float* __restrict__ logits,
    const int* __restrict__ visited, const int* __restrict__ prev_node,
    const int* __restrict__ all_visited, const float* __restrict__ ew,
    const float* __restrict__ sb_p, const float* __restrict__ rp_p,
    float* __restrict__ out) {
  const int x = blockIdx.x, b = blockIdx.y, t = threadIdx.x;
  const int g = t >> 5, l = t & 31;
  const float4 lg = *(const float4*)(logits + b * EE + l * 4);
  const bool av = all_visited[b] != 0;
  const int pv = prev_node[b];
  const float direct = av ? ew[((size_t)b * NN + pv) * NN] : 1.f;
  const float sbv = sb_p[0], rpv = rp_p[0];
  const int nb = x * CHN;
#pragma unroll 4
  for (int i = 0; i < 16; ++i) {
    const int nl = i * 8 + g;
    if (nl < CHN) {
      const int n = nb + nl;
      const float4 a = *(const float4*)(ne + ((size_t)b * NN + n) * EE + l * 4);
      float d = a.x * lg.x + a.y * lg.y + a.z * lg.z + a.w * lg.w;
#pragma unroll
      for (int k = 16; k >= 1; k >>= 1) d += __shfl_xor(d, k, 32);
      if (l == 0) {
        float sc = d;
        if (!av) {
          if (visited[b * NN + n] != 0) sc = rpv;
        } else {
          const float via = ew[((size_t)b * NN + pv) * NN + n] + ew[((size_t)b * NN + n) * NN];
          if (via < direct) sc += sbv * (direct - via) / direct;
        }
        out[b * NN + n] = sc;
      }
    }
  }
}

extern "C" void kernel_launch(void* const* d_in, const int* in_sizes, int n_in,
                              void* d_out, int out_size, void* d_ws, size_t ws_size,
                              hipStream_t stream) {
  const float* ds   = (const float*)d_in[0];
  const float* ne   = (const float*)d_in[1];
  const int*   mask = (const int*)d_in[2];
  const float* ew   = (const float*)d_in[3];
  const int*   visited = (const int*)d_in[4];
  const int*   prev = (const int*)d_in[5];
  const int*   allv = (const int*)d_in[6];
  const float* Wq = (const float*)d_in[7];
  const float* bq = (const float*)d_in[8];
  const float* Wk = (const float*)d_in[9];
  const float* bk = (const float*)d_in[10];
  const float* Wv = (const float*)d_in[11];
  const float* bv = (const float*)d_in[12];
  const float* Wo = (const float*)d_in[13];
  const float* bo = (const float*)d_in[14];
  const float* Wp = (const float*)d_in[15];
  const float* bp = (const float*)d_in[16];
  const float* ln_g = (const float*)d_in[17];
  const float* ln_b = (const float*)d_in[18];
  const float* sb = (const float*)d_in[19];
  const float* rp = (const float*)d_in[20];
  float* out = (float*)d_out;
  float* ws = (float*)d_ws;

  float* pctx   = ws;
  float* pm     = ws + 524288;
  float* ps     = ws + 528384;
  float* logits = ws + 532480;

  k_fused_att<<<dim3(NCH, BB), 256, 0, stream>>>(ds, ne, mask, Wq, bq, Wk, bk, pctx, pm, ps);
  k_head<<<BB, 128, 0, stream>>>(pctx, pm, ps, Wv, bv, Wo, bo, Wp, bp, ln_g, ln_b, logits);
  k_scores<<<dim3(16, BB), 256, 0, stream>>>(ne, logits, visited, prev, allv, ew, sb, rp, out);
}